// Round 1
// baseline (573.236 us; speedup 1.0000x reference)
//
#include <hip/hip_runtime.h>
#include <hip/hip_bf16.h>

// Fused GRU-like cell: 200000 rows, IN=HID=256, fp32 in/out, bf16 MFMA compute.
// Kernel 1 (wconv): convert weights fp32->bf16 into d_ws, combine biases.
// Kernel 2 (gru):   per-block 64 rows, fully fused 6-stage MFMA pipeline.

typedef short bf16x8 __attribute__((ext_vector_type(8)));   // 8 bf16 = 4 VGPRs
typedef float f32x4  __attribute__((ext_vector_type(4)));

__device__ __forceinline__ unsigned int rne_bf16(float f) {
  unsigned int u = __builtin_bit_cast(unsigned int, f);
  return (u + 0x7fffu + ((u >> 16) & 1u)) >> 16;
}
__device__ __forceinline__ unsigned int pack2(float a, float b) {
  return rne_bf16(a) | (rne_bf16(b) << 16);
}
__device__ __forceinline__ float bf2f(unsigned short s) {
  unsigned int u = ((unsigned int)s) << 16;
  return __builtin_bit_cast(float, u);
}

// ws layout (bf16 elements):
//   Bz = [Wz|Uz] 256x512 @ 0
//   Br = [Wr|Ur] 256x512 @ 131072
//   Wh 256x256 @ 262144, Uh @ 327680, G @ 393216, L @ 458752
// then fp32 biases @ byte 1048576: bzc, brc, bcc, bg, bl (5 x 256)
__global__ void wconv_kernel(const float* Wz, const float* Uz, const float* Wr, const float* Ur,
                             const float* Wh, const float* Uh, const float* G, const float* L,
                             const float* bWz, const float* bUz, const float* bWr, const float* bUr,
                             const float* bWh, const float* bUh, const float* bG, const float* bL,
                             const float* bias_h,
                             unsigned short* wb, float* bout) {
  int gid = blockIdx.x * blockDim.x + threadIdx.x;
  const int total = 524288;
  for (int e = gid; e < total; e += gridDim.x * blockDim.x) {
    float v;
    if (e < 131072) {                     // Bz 256x512
      int n = e >> 9, k = e & 511;
      v = (k < 256) ? Wz[n * 256 + k] : Uz[n * 256 + (k - 256)];
    } else if (e < 262144) {              // Br 256x512
      int e2 = e - 131072;
      int n = e2 >> 9, k = e2 & 511;
      v = (k < 256) ? Wr[n * 256 + k] : Ur[n * 256 + (k - 256)];
    } else {                              // Wh, Uh, G, L (row-major 256x256)
      int e2 = e - 262144;
      int m = e2 >> 16, idx = e2 & 65535;
      const float* mats[4] = {Wh, Uh, G, L};
      v = mats[m][idx];
    }
    wb[e] = (unsigned short)rne_bf16(v);
  }
  if (gid < 256) {
    bout[gid]        = bWz[gid] + bUz[gid];
    bout[256 + gid]  = bWr[gid] + bUr[gid];
    bout[512 + gid]  = bWh[gid] + bUh[gid] + bias_h[gid];
    bout[768 + gid]  = bG[gid];
    bout[1024 + gid] = bL[gid];
  }
}

// Main fused kernel. 512 threads (8 waves). BM=64 rows/block.
// Wave w owns output cols [32w, 32w+32). MFMA 16x16x32 bf16.
// LDS: xh[64][512] bf16 (x cols 0..255, h cols 256..511), XOR-swizzled 16B chunks.
//      cbuf[64][256] bf16 (rh, then cand), swizzled.
__global__ __launch_bounds__(512, 2) void gru_kernel(
    const float* __restrict__ x, const float* __restrict__ h,
    const unsigned short* __restrict__ wb,
    const float* __restrict__ bia,
    float* __restrict__ out)
{
  __shared__ unsigned short xh[64 * 512];    // 64 KB
  __shared__ unsigned short cbuf[64 * 256];  // 32 KB

  const int tid  = threadIdx.x;
  const int lane = tid & 63;
  const int wave = tid >> 6;
  const int q    = lane >> 4;     // quarter-wave id
  const int lr   = lane & 15;
  const long row0 = (long)blockIdx.x * 64;

  // ---------------- Phase 0: stage x,h -> LDS bf16 (swizzled) ----------------
#pragma unroll
  for (int i = 0; i < 4; ++i) {
    int c = tid + i * 512;               // chunk id: 64 rows x 32 chunks
    int r = c >> 5, c8 = c & 31;
    const float4* p = reinterpret_cast<const float4*>(x + (row0 + r) * 256 + c8 * 8);
    float4 v0 = p[0], v1 = p[1];
    uint4 w;
    w.x = pack2(v0.x, v0.y); w.y = pack2(v0.z, v0.w);
    w.z = pack2(v1.x, v1.y); w.w = pack2(v1.z, v1.w);
    reinterpret_cast<uint4*>(xh)[r * 64 + (c8 ^ (r & 7))] = w;
  }
#pragma unroll
  for (int i = 0; i < 4; ++i) {
    int c = tid + i * 512;
    int r = c >> 5, c8 = c & 31;
    const float4* p = reinterpret_cast<const float4*>(h + (row0 + r) * 256 + c8 * 8);
    float4 v0 = p[0], v1 = p[1];
    uint4 w;
    w.x = pack2(v0.x, v0.y); w.y = pack2(v0.z, v0.w);
    w.z = pack2(v1.x, v1.y); w.w = pack2(v1.z, v1.w);
    reinterpret_cast<uint4*>(xh)[r * 64 + ((32 + c8) ^ (r & 7))] = w;
  }
  __syncthreads();

  const unsigned short* Bz = wb;
  const unsigned short* Br = wb + 131072;
  const unsigned short* Wh = wb + 262144;
  const unsigned short* Uh = wb + 327680;
  const unsigned short* Gw = wb + 393216;
  const unsigned short* Lw = wb + 458752;

  auto ldsA = [&](int mt, int ks) -> bf16x8 {  // from xh (row stride 64 chunks)
    int r = mt * 16 + lr;
    int kc = ks * 4 + q;
    return reinterpret_cast<const bf16x8*>(xh)[r * 64 + (kc ^ (r & 7))];
  };
  auto ldsC = [&](int mt, int ks) -> bf16x8 {  // from cbuf (row stride 32 chunks)
    int r = mt * 16 + lr;
    int kc = ks * 4 + q;
    return reinterpret_cast<const bf16x8*>(cbuf)[r * 32 + (kc ^ (r & 7))];
  };
  auto ldB = [&](const unsigned short* base, int stride, int ct, int ks) -> bf16x8 {
    int n = wave * 32 + ct * 16 + lr;
    int k0 = ks * 32 + q * 8;
    return *reinterpret_cast<const bf16x8*>(base + (size_t)n * stride + k0);
  };

  // ---------------- Phase 1: z, r (K=512) and x@Wh^T (K=256) ----------------
  f32x4 az[4][2] = {}; f32x4 ar[4][2] = {}; f32x4 ac[4][2] = {};

#pragma unroll 2
  for (int ks = 0; ks < 16; ++ks) {
    bf16x8 a[4];
#pragma unroll
    for (int mt = 0; mt < 4; ++mt) a[mt] = ldsA(mt, ks);
#pragma unroll
    for (int ct = 0; ct < 2; ++ct) {
      bf16x8 b = ldB(Bz, 512, ct, ks);
#pragma unroll
      for (int mt = 0; mt < 4; ++mt)
        az[mt][ct] = __builtin_amdgcn_mfma_f32_16x16x32_bf16(a[mt], b, az[mt][ct], 0, 0, 0);
    }
#pragma unroll
    for (int ct = 0; ct < 2; ++ct) {
      bf16x8 b = ldB(Br, 512, ct, ks);
#pragma unroll
      for (int mt = 0; mt < 4; ++mt)
        ar[mt][ct] = __builtin_amdgcn_mfma_f32_16x16x32_bf16(a[mt], b, ar[mt][ct], 0, 0, 0);
    }
    if (ks < 8) {  // x region only (k < 256)
#pragma unroll
      for (int ct = 0; ct < 2; ++ct) {
        bf16x8 b = ldB(Wh, 256, ct, ks);
#pragma unroll
        for (int mt = 0; mt < 4; ++mt)
          ac[mt][ct] = __builtin_amdgcn_mfma_f32_16x16x32_bf16(a[mt], b, ac[mt][ct], 0, 0, 0);
      }
    }
  }

  const int col0 = wave * 32 + lr;      // ct=0 column
  // z = sigmoid(.); r = sigmoid(.); rh = r*h -> cbuf (bf16)
#pragma unroll
  for (int mt = 0; mt < 4; ++mt) {
#pragma unroll
    for (int ct = 0; ct < 2; ++ct) {
      int cg = col0 + ct * 16;
      float bzc = bia[cg];
      float brc = bia[256 + cg];
#pragma unroll
      for (int i = 0; i < 4; ++i) {
        int rl = mt * 16 + q * 4 + i;
        float zp = az[mt][ct][i] + bzc;
        az[mt][ct][i] = 1.f / (1.f + __expf(-zp));      // keep z in regs
        float rp = ar[mt][ct][i] + brc;
        float rv = 1.f / (1.f + __expf(-rp));
        int hc = 32 + (cg >> 3);
        float hval = bf2f(xh[rl * 512 + (hc ^ (rl & 7)) * 8 + (cg & 7)]);
        float rh = rv * hval;
        cbuf[rl * 256 + (((cg >> 3) ^ (rl & 7)) * 8) + (cg & 7)] = (unsigned short)rne_bf16(rh);
      }
    }
  }
  __syncthreads();

  // ---------------- Phase 2: cand += rh @ Uh^T (K=256) ----------------
#pragma unroll 2
  for (int ks = 0; ks < 8; ++ks) {
    bf16x8 a[4];
#pragma unroll
    for (int mt = 0; mt < 4; ++mt) a[mt] = ldsC(mt, ks);
#pragma unroll
    for (int ct = 0; ct < 2; ++ct) {
      bf16x8 b = ldB(Uh, 256, ct, ks);
#pragma unroll
      for (int mt = 0; mt < 4; ++mt)
        ac[mt][ct] = __builtin_amdgcn_mfma_f32_16x16x32_bf16(a[mt], b, ac[mt][ct], 0, 0, 0);
    }
  }
  __syncthreads();   // all reads of rh done before overwrite

  // cand = ac + bias; write bf16 into cbuf
#pragma unroll
  for (int mt = 0; mt < 4; ++mt) {
#pragma unroll
    for (int ct = 0; ct < 2; ++ct) {
      int cg = col0 + ct * 16;
      float bcc = bia[512 + cg];
#pragma unroll
      for (int i = 0; i < 4; ++i) {
        int rl = mt * 16 + q * 4 + i;
        float cd = ac[mt][ct][i] + bcc;
        cbuf[rl * 256 + (((cg >> 3) ^ (rl & 7)) * 8) + (cg & 7)] = (unsigned short)rne_bf16(cd);
      }
    }
  }
  __syncthreads();

  // ---------------- Phase 3: gate & linear (K=256 each) ----------------
  f32x4 ag[4][2] = {}; f32x4 al[4][2] = {};
#pragma unroll 2
  for (int ks = 0; ks < 8; ++ks) {
    bf16x8 a[4];
#pragma unroll
    for (int mt = 0; mt < 4; ++mt) a[mt] = ldsC(mt, ks);
#pragma unroll
    for (int ct = 0; ct < 2; ++ct) {
      bf16x8 b = ldB(Gw, 256, ct, ks);
#pragma unroll
      for (int mt = 0; mt < 4; ++mt)
        ag[mt][ct] = __builtin_amdgcn_mfma_f32_16x16x32_bf16(a[mt], b, ag[mt][ct], 0, 0, 0);
    }
#pragma unroll
    for (int ct = 0; ct < 2; ++ct) {
      bf16x8 b = ldB(Lw, 256, ct, ks);
#pragma unroll
      for (int mt = 0; mt < 4; ++mt)
        al[mt][ct] = __builtin_amdgcn_mfma_f32_16x16x32_bf16(a[mt], b, al[mt][ct], 0, 0, 0);
    }
  }

  // ---------------- Phase 4: epilogue ----------------
#pragma unroll
  for (int mt = 0; mt < 4; ++mt) {
#pragma unroll
    for (int ct = 0; ct < 2; ++ct) {
      int cg = col0 + ct * 16;
      float bgc = bia[768 + cg];
      float blc = bia[1024 + cg];
#pragma unroll
      for (int i = 0; i < 4; ++i) {
        int rl = mt * 16 + q * 4 + i;
        float gv = 1.f / (1.f + __expf(-(ag[mt][ct][i] + bgc)));
        float lv = al[mt][ct][i] + blc;
        float cand = lv * gv;
        int hc = 32 + (cg >> 3);
        float hval = bf2f(xh[rl * 512 + (hc ^ (rl & 7)) * 8 + (cg & 7)]);
        float zv = az[mt][ct][i];
        out[(row0 + rl) * 256 + cg] = zv * cand + (1.f - zv) * hval;
      }
    }
  }
}

extern "C" void kernel_launch(void* const* d_in, const int* in_sizes, int n_in,
                              void* d_out, int out_size, void* d_ws, size_t ws_size,
                              hipStream_t stream) {
  const float* x   = (const float*)d_in[0];
  const float* h   = (const float*)d_in[1];
  const float* Wz  = (const float*)d_in[2];  const float* bWz = (const float*)d_in[3];
  const float* Uz  = (const float*)d_in[4];  const float* bUz = (const float*)d_in[5];
  const float* Wr  = (const float*)d_in[6];  const float* bWr = (const float*)d_in[7];
  const float* Ur  = (const float*)d_in[8];  const float* bUr = (const float*)d_in[9];
  const float* Wh  = (const float*)d_in[10]; const float* bWh = (const float*)d_in[11];
  const float* Uh  = (const float*)d_in[12]; const float* bUh = (const float*)d_in[13];
  const float* G   = (const float*)d_in[14]; const float* bG  = (const float*)d_in[15];
  const float* L   = (const float*)d_in[16]; const float* bL  = (const float*)d_in[17];
  const float* bh  = (const float*)d_in[18];

  unsigned short* wb = (unsigned short*)d_ws;
  float* bia = (float*)((char*)d_ws + 1048576);

  wconv_kernel<<<512, 512, 0, stream>>>(Wz, Uz, Wr, Ur, Wh, Uh, G, L,
                                        bWz, bUz, bWr, bUr, bWh, bUh, bG, bL, bh,
                                        wb, bia);

  int rows = in_sizes[0] / 256;        // 200000
  int grid = rows / 64;                // 3125 (exact)
  gru_kernel<<<grid, 512, 0, stream>>>(x, h, wb, bia, (float*)d_out);
}